// Round 17
// baseline (152.369 us; speedup 1.0000x reference)
//
#include <hip/hip_runtime.h>
#include <math.h>

#define BB_ 8
#define CC_ 256
#define LL_ 2048
#define HEADS_ 4
#define DHEAD_ 32
#define HID_ 128
#define EPS_ 1e-5f
#define SCALE_ 0.17677669529663687f   // 32^-0.5
#define K1_ (SCALE_ * 1.44269504088896f)   // folded into Wq at prep time

typedef short v8s  __attribute__((ext_vector_type(8)));
typedef float v4f  __attribute__((ext_vector_type(4)));
typedef float v16f __attribute__((ext_vector_type(16)));
typedef unsigned v4u __attribute__((ext_vector_type(4)));

__device__ inline short f2bf(float x) {   // RNE f32 -> bf16 bits
    union { float f; unsigned u; } a; a.f = x;
    unsigned r = a.u + 0x7fffu + ((a.u >> 16) & 1u);
    return (short)(r >> 16);
}
__device__ inline unsigned fbits(float x) { union { float f; unsigned u; } a; a.f = x; return a.u; }

// ---------------------------------------------------------------------------
// Kernel 0: weight prep (unchanged r16).
// ---------------------------------------------------------------------------
__global__ __launch_bounds__(256) void k_prep(
    const float* __restrict__ Wq, const float* __restrict__ Wk, const float* __restrict__ Wv,
    const float* __restrict__ Wo, const float* __restrict__ g, const float* __restrict__ bvec,
    short* __restrict__ wqkv, short* __restrict__ wo, float2* __restrict__ gb)
{
    __shared__ float red0[4], red1[4];
    const int blk = blockIdx.x, c = threadIdx.x;
    const int wave = c >> 6, lane = c & 63;
    if (blk < 384) {
        const float* W; int oo; float scale = 1.f;
        if (blk < 128)      { W = Wq; oo = blk;       scale = K1_; }
        else if (blk < 256) { W = Wk; oo = blk - 128; }
        else                { W = Wv; oo = blk - 256; }
        float w  = W[oo * 256 + c] * scale;
        float wg = w * g[c];
        wqkv[blk * 256 + c] = f2bf(wg);
        float r0 = wg, r1 = w * bvec[c];
        #pragma unroll
        for (int off = 1; off < 64; off <<= 1) {
            r0 += __shfl_xor(r0, off, 64);
            r1 += __shfl_xor(r1, off, 64);
        }
        if (lane == 0) { red0[wave] = r0; red1[wave] = r1; }
        __syncthreads();
        if (c == 0)
            gb[blk] = make_float2(red0[0] + red0[1] + red0[2] + red0[3],
                                  red1[0] + red1[1] + red1[2] + red1[3]);
    } else {
        int i2 = (blk - 384) * 256 + c;
        wo[i2] = f2bf(Wo[i2]);
    }
}

// ---------------------------------------------------------------------------
// Kernel 1: LayerNorm-folded QKV projection (unchanged r16).
// ---------------------------------------------------------------------------
__global__ __launch_bounds__(512) void k_ln_qkv(
    const float* __restrict__ x, const short* __restrict__ wqkv, const float2* __restrict__ gb,
    short* __restrict__ q, short* __restrict__ k, short* __restrict__ v)
{
    __shared__ short xnT[32 * 264];
    __shared__ short st2[128 * 48];
    __shared__ float ps_[8 * 32], ps2_[8 * 32];
    const int b   = blockIdx.y;
    const int l0  = blockIdx.x * 32;
    const int tid = threadIdx.x;
    const int wave = tid >> 6, lane = tid & 63;

    {
        const int ls = tid & 31;
        const int cg = tid >> 5;
        float s = 0.f, s2 = 0.f;
        #pragma unroll
        for (int kk = 0; kk < 8; ++kk) {
            int c = 2 * cg + 32 * kk;
            float t0 = x[((size_t)b * CC_ + c) * LL_ + l0 + ls];
            float t1 = x[((size_t)b * CC_ + c + 1) * LL_ + l0 + ls];
            s += t0 + t1; s2 += t0 * t0 + t1 * t1;
            unsigned pk = (unsigned short)f2bf(t0) | ((unsigned)(unsigned short)f2bf(t1) << 16);
            *(unsigned*)(xnT + ls * 264 + c) = pk;
        }
        s  += __shfl_xor(s, 32, 64);
        s2 += __shfl_xor(s2, 32, 64);
        if (lane < 32) { ps_[wave * 32 + lane] = s; ps2_[wave * 32 + lane] = s2; }
    }
    __syncthreads();

    const int n = lane & 15, quad = lane >> 4;
    const int rowbase = (wave >> 2) * 16;
    const int colbase = (wave & 3) * 96;

    v4f acc[6];
    #pragma unroll
    for (int ct = 0; ct < 6; ++ct) acc[ct] = (v4f){0.f, 0.f, 0.f, 0.f};

    #pragma unroll
    for (int ks = 0; ks < 8; ++ks) {
        const v8s af = *(const v8s*)(xnT + (rowbase + n) * 264 + ks * 32 + quad * 8);
        #pragma unroll
        for (int ct = 0; ct < 6; ++ct) {
            const v8s bfrag = *(const v8s*)(wqkv + (size_t)(colbase + ct * 16 + n) * 256 + ks * 32 + quad * 8);
            acc[ct] = __builtin_amdgcn_mfma_f32_16x16x32_bf16(af, bfrag, acc[ct], 0, 0, 0);
        }
    }
    __syncthreads();

    float rsv[4], rmv[4];
    #pragma unroll
    for (int r = 0; r < 4; ++r) {
        int l = rowbase + quad * 4 + r;
        float s = 0.f, s2 = 0.f;
        #pragma unroll
        for (int p = 0; p < 8; ++p) { s += ps_[p * 32 + l]; s2 += ps2_[p * 32 + l]; }
        float mean = s * (1.f / CC_);
        float var  = s2 * (1.f / CC_) - mean * mean;
        float rs   = rsqrtf(var + EPS_);
        rsv[r] = rs; rmv[r] = rs * mean;
    }
    #pragma unroll
    for (int ct = 0; ct < 6; ++ct) {
        int o = colbase + ct * 16 + n;
        float2 gbo = gb[o];
        #pragma unroll
        for (int r = 0; r < 4; ++r) {
            int l = rowbase + quad * 4 + r;
            float val = rsv[r] * acc[ct][r] - rmv[r] * gbo.x + gbo.y;
            if (o < 256)      xnT[l * 264 + o] = f2bf(val);
            else              st2[(o - 256) * 48 + l] = f2bf(val);
        }
    }
    __syncthreads();

    {
        int u = tid;
        int h = u >> 7, rest = u & 127;
        int l = rest >> 2, dg = rest & 3;
        size_t bh = (size_t)b * HEADS_ + h;
        v8s qv = *(const v8s*)(xnT + l * 264 + h * 32 + dg * 8);
        *(v8s*)(q + (bh * LL_ + l0 + l) * DHEAD_ + dg * 8) = qv;
        v8s kv = *(const v8s*)(xnT + l * 264 + 128 + h * 32 + dg * 8);
        *(v8s*)(k + (bh * LL_ + l0 + l) * DHEAD_ + dg * 8) = kv;

        int op = u >> 2, lg = u & 3;
        v8s vv = *(const v8s*)(st2 + op * 48 + lg * 8);
        int h2 = op >> 5, d = op & 31;
        *(v8s*)(v + (((size_t)b * HEADS_ + h2) * DHEAD_ + d) * LL_ + l0 + lg * 8) = vv;
    }
}

// ---------------------------------------------------------------------------
// Kernel 2: flash attention. 256 thr = 2 q-waves x 2 key-halves, q-tile 64.
// Grid 1024 blocks -> 4 blocks/CU (was 2): smaller barrier groups + block
// interleaving hides chunk-barrier drains. Register-dbuf staging kept:
// each thread stages one 64B K-row piece + one 64B V-quarter (4x b128).
// ---------------------------------------------------------------------------
__global__ __launch_bounds__(256) void k_attn(
    const short* __restrict__ q, const short* __restrict__ k, const short* __restrict__ v,
    short* __restrict__ ao)
{
    __shared__ char smem[20480 + 17408 + 256];
    short* Kb     = (short*)smem;                      // [2][128*40]  (hh*5120)
    short* Vb     = (short*)(smem + 20480);            // [2][32*136]  (hh*4352)
    float* Ost    = (float*)smem;                      // alias Kb: [2][32][32]
    float* psumst = (float*)(smem + 20480 + 17408);    // [2*32]

    const int bh   = blockIdx.y;
    const int b    = bh >> 2, h = bh & 3;
    const int tid  = threadIdx.x;
    const int wave = tid >> 6, lane = tid & 63;
    const int wq   = wave & 1;           // q-subtile (2 per block)
    const int kh   = wave >> 1;          // key half: [kh*1024, +1024)
    const int m    = lane & 31;
    const int half = lane >> 5;
    const size_t kvbase = (size_t)bh * LL_ * DHEAD_;   // q,k: [bh][l][32]
    const size_t vbase  = (size_t)bh * DHEAD_ * LL_;   // v:   [bh][d][L]

    const int q0 = blockIdx.x * 64 + wq * 32;

    const v8s qf0 = *(const v8s*)(q + kvbase + (size_t)(q0 + m) * DHEAD_ + half * 8);
    const v8s qf1 = *(const v8s*)(q + kvbase + (size_t)(q0 + m) * DHEAD_ + 16 + half * 8);

    v16f O = {};
    float psum = 0.f;

    // staging coords: K: thread -> one key row (64B); V: thread -> one
    // 64B quarter of a d-row. Both halves staged by the whole block.
    const int s_hh = tid >> 7, s_r = tid & 127;
    const int v_hh = tid >> 7, v_d = (tid >> 2) & 31, v_q = tid & 3;

    const short* ksrc0 = k + kvbase + (size_t)(s_hh * 1024 + s_r) * DHEAD_;
    const short* vsrc0 = v + vbase + (size_t)v_d * LL_ + v_hh * 1024 + v_q * 32;
    short* kdst = Kb + s_hh * 5120 + s_r * 40;
    short* vdst = Vb + v_hh * 4352 + v_d * 136 + v_q * 32;

    // prologue: chunk 0 into registers
    v8s kr[4], vr[4];
    #pragma unroll
    for (int j = 0; j < 4; ++j) {
        kr[j] = *(const v8s*)(ksrc0 + j * 8);
        vr[j] = *(const v8s*)(vsrc0 + j * 8);
    }

    for (int kc = 0; kc < 1024; kc += 128) {
        __syncthreads();   // previous chunk's readers done
        #pragma unroll
        for (int j = 0; j < 4; ++j) {
            *(v8s*)(kdst + j * 8) = kr[j];
            *(v8s*)(vdst + j * 8) = vr[j];
        }
        if (kc < 896) {    // prefetch next chunk; completes during compute
            const short* kn = ksrc0 + (size_t)(kc + 128) * DHEAD_;
            const short* vn = vsrc0 + (kc + 128);
            #pragma unroll
            for (int j = 0; j < 4; ++j) {
                kr[j] = *(const v8s*)(kn + j * 8);
                vr[j] = *(const v8s*)(vn + j * 8);
            }
        }
        __syncthreads();   // staging visible

        const short* Kw = Kb + kh * 5120;
        const short* Vw = Vb + kh * 4352;
        #pragma unroll
        for (int ktl = 0; ktl < 128; ktl += 32) {
            const v8s kf0 = *(const v8s*)(Kw + (ktl + m) * 40 + half * 8);
            const v8s kf1 = *(const v8s*)(Kw + (ktl + m) * 40 + 16 + half * 8);
            v16f S = __builtin_amdgcn_mfma_f32_32x32x16_bf16(kf0, qf0, (v16f){}, 0, 0, 0);
            S      = __builtin_amdgcn_mfma_f32_32x32x16_bf16(kf1, qf1, S,        0, 0, 0);

            const v8s vf0 = *(const v8s*)(Vw + m * 136 + ktl + half * 8);
            const v8s vf1 = *(const v8s*)(Vw + m * 136 + ktl + 16 + half * 8);

            unsigned e[8];
            #pragma unroll
            for (int i = 0; i < 8; ++i) {
                float pa = __builtin_amdgcn_exp2f(S[2 * i]);
                float pb = __builtin_amdgcn_exp2f(S[2 * i + 1]);
                psum += pa + pb;
                e[i] = __builtin_amdgcn_perm(fbits(pb) + 0x8000u, fbits(pa) + 0x8000u, 0x07060302u);
            }
            v4u f1, f2;
#if __has_builtin(__builtin_amdgcn_permlane32_swap)
            {
                auto r02 = __builtin_amdgcn_permlane32_swap(e[0], e[2], false, false);
                auto r13 = __builtin_amdgcn_permlane32_swap(e[1], e[3], false, false);
                auto r46 = __builtin_amdgcn_permlane32_swap(e[4], e[6], false, false);
                auto r57 = __builtin_amdgcn_permlane32_swap(e[5], e[7], false, false);
                f1 = (v4u){r02[0], r13[0], r02[1], r13[1]};
                f2 = (v4u){r46[0], r57[0], r46[1], r57[1]};
            }
#else
            {
                unsigned o0 = __shfl_xor(e[0], 32, 64), o1 = __shfl_xor(e[1], 32, 64);
                unsigned o2 = __shfl_xor(e[2], 32, 64), o3 = __shfl_xor(e[3], 32, 64);
                unsigned o4 = __shfl_xor(e[4], 32, 64), o5 = __shfl_xor(e[5], 32, 64);
                unsigned o6 = __shfl_xor(e[6], 32, 64), o7 = __shfl_xor(e[7], 32, 64);
                f1 = half ? (v4u){o2, o3, e[2], e[3]} : (v4u){e[0], e[1], o0, o1};
                f2 = half ? (v4u){o6, o7, e[6], e[7]} : (v4u){e[4], e[5], o4, o5};
            }
#endif
            O = __builtin_amdgcn_mfma_f32_32x32x16_bf16(__builtin_bit_cast(v8s, f1), vf0, O, 0, 0, 0);
            O = __builtin_amdgcn_mfma_f32_32x32x16_bf16(__builtin_bit_cast(v8s, f2), vf1, O, 0, 0, 0);
        }
    }

    psum += __shfl_xor(psum, 32, 64);    // lane m: den-partial for q = m

    __syncthreads();   // all waves done reading Kb before Ost (alias) writes
    if (kh == 1) {
        #pragma unroll
        for (int r = 0; r < 16; ++r) {
            int qr = (r & 3) + 8 * (r >> 2) + 4 * half;
            Ost[(wq * 32 + qr) * 32 + m] = O[r];
        }
        if (half == 0) psumst[wq * 32 + m] = psum;
    }
    __syncthreads();
    if (kh == 0) {
        float den = psum + psumst[wq * 32 + m];
        float invden = 1.f / den;
        #pragma unroll
        for (int r = 0; r < 16; ++r) {
            int qr = (r & 3) + 8 * (r >> 2) + 4 * half;
            float inv = __shfl(invden, qr, 64);
            float val = (O[r] + Ost[(wq * 32 + qr) * 32 + m]) * inv;
            int row = q0 + qr;
            ao[((size_t)b * LL_ + row) * HID_ + h * DHEAD_ + m] = f2bf(val);
        }
    }
}

// ---------------------------------------------------------------------------
// Kernel 3: output projection (unchanged r16).
// ---------------------------------------------------------------------------
__global__ __launch_bounds__(256) void k_oproj(
    const short* __restrict__ ao, const short* __restrict__ wo, const float* __restrict__ bo,
    const float* __restrict__ x, float* __restrict__ out)
{
    const int b = blockIdx.z;
    const int l0 = blockIdx.x * 32;
    const int tid = threadIdx.x;
    const int wave = tid >> 6, lane = tid & 63;
    const int m = lane & 31, half = lane >> 5;
    const int o0 = blockIdx.y * 128 + wave * 32;

    float xv[16]; float bv_[16];
    #pragma unroll
    for (int r = 0; r < 16; ++r) {
        int o = o0 + (r & 3) + 8 * (r >> 2) + 4 * half;
        xv[r]  = x[((size_t)b * CC_ + o) * LL_ + l0 + m];
        bv_[r] = bo[o];
    }

    v8s bf[8];
    #pragma unroll
    for (int ks = 0; ks < 8; ++ks)
        bf[ks] = *(const v8s*)(ao + ((size_t)b * LL_ + l0 + m) * HID_ + ks * 16 + half * 8);

    v16f acc = {};
    #pragma unroll
    for (int ks = 0; ks < 8; ++ks) {
        const v8s af = *(const v8s*)(wo + (size_t)(o0 + m) * HID_ + ks * 16 + half * 8);
        acc = __builtin_amdgcn_mfma_f32_32x32x16_bf16(af, bf[ks], acc, 0, 0, 0);
    }

    #pragma unroll
    for (int r = 0; r < 16; ++r) {
        int o = o0 + (r & 3) + 8 * (r >> 2) + 4 * half;
        size_t oi = ((size_t)b * CC_ + o) * LL_ + l0 + m;
        out[oi] = acc[r] + bv_[r] + xv[r];
    }
}

extern "C" void kernel_launch(void* const* d_in, const int* in_sizes, int n_in,
                              void* d_out, int out_size, void* d_ws, size_t ws_size,
                              hipStream_t stream) {
    const float* x  = (const float*)d_in[0];
    const float* g  = (const float*)d_in[1];
    const float* bv = (const float*)d_in[2];
    const float* Wq = (const float*)d_in[3];
    const float* Wk = (const float*)d_in[4];
    const float* Wv = (const float*)d_in[5];
    const float* Wo = (const float*)d_in[6];
    const float* bo = (const float*)d_in[7];
    float* out = (float*)d_out;

    const size_t qkv_elems = (size_t)BB_ * HEADS_ * LL_ * DHEAD_;
    short* q    = (short*)d_ws;
    short* k    = q + qkv_elems;
    short* v    = k + qkv_elems;
    short* ao   = v + qkv_elems;
    short* wqkv = ao + qkv_elems;
    short* wo   = wqkv + 384 * 256;
    float2* gb  = (float2*)(wo + 256 * 128);

    k_prep  <<<dim3(512), dim3(256), 0, stream>>>(Wq, Wk, Wv, Wo, g, bv, wqkv, wo, gb);
    k_ln_qkv<<<dim3(LL_ / 32, BB_), dim3(512), 0, stream>>>(x, wqkv, gb, q, k, v);
    k_attn  <<<dim3(LL_ / 64, BB_ * HEADS_), dim3(256), 0, stream>>>(q, k, v, ao);
    k_oproj <<<dim3(LL_ / 32, 2, BB_), dim3(256), 0, stream>>>(ao, wo, bo, x, out);
}

// Round 18
// 145.522 us; speedup vs baseline: 1.0471x; 1.0471x over previous
//
#include <hip/hip_runtime.h>
#include <math.h>

#define BB_ 8
#define CC_ 256
#define LL_ 2048
#define HEADS_ 4
#define DHEAD_ 32
#define HID_ 128
#define EPS_ 1e-5f
#define SCALE_ 0.17677669529663687f   // 32^-0.5
#define K1_ (SCALE_ * 1.44269504088896f)   // folded into Wq at prep time

typedef short v8s  __attribute__((ext_vector_type(8)));
typedef float v4f  __attribute__((ext_vector_type(4)));
typedef float v16f __attribute__((ext_vector_type(16)));
typedef unsigned v4u __attribute__((ext_vector_type(4)));

__device__ inline short f2bf(float x) {   // RNE f32 -> bf16 bits
    union { float f; unsigned u; } a; a.f = x;
    unsigned r = a.u + 0x7fffu + ((a.u >> 16) & 1u);
    return (short)(r >> 16);
}
__device__ inline unsigned fbits(float x) { union { float f; unsigned u; } a; a.f = x; return a.u; }

// ---------------------------------------------------------------------------
// Kernel 0: weight prep (unchanged r16).
// ---------------------------------------------------------------------------
__global__ __launch_bounds__(256) void k_prep(
    const float* __restrict__ Wq, const float* __restrict__ Wk, const float* __restrict__ Wv,
    const float* __restrict__ Wo, const float* __restrict__ g, const float* __restrict__ bvec,
    short* __restrict__ wqkv, short* __restrict__ wo, float2* __restrict__ gb)
{
    __shared__ float red0[4], red1[4];
    const int blk = blockIdx.x, c = threadIdx.x;
    const int wave = c >> 6, lane = c & 63;
    if (blk < 384) {
        const float* W; int oo; float scale = 1.f;
        if (blk < 128)      { W = Wq; oo = blk;       scale = K1_; }
        else if (blk < 256) { W = Wk; oo = blk - 128; }
        else                { W = Wv; oo = blk - 256; }
        float w  = W[oo * 256 + c] * scale;
        float wg = w * g[c];
        wqkv[blk * 256 + c] = f2bf(wg);
        float r0 = wg, r1 = w * bvec[c];
        #pragma unroll
        for (int off = 1; off < 64; off <<= 1) {
            r0 += __shfl_xor(r0, off, 64);
            r1 += __shfl_xor(r1, off, 64);
        }
        if (lane == 0) { red0[wave] = r0; red1[wave] = r1; }
        __syncthreads();
        if (c == 0)
            gb[blk] = make_float2(red0[0] + red0[1] + red0[2] + red0[3],
                                  red1[0] + red1[1] + red1[2] + red1[3]);
    } else {
        int i2 = (blk - 384) * 256 + c;
        wo[i2] = f2bf(Wo[i2]);
    }
}

// ---------------------------------------------------------------------------
// Kernel 1: LayerNorm-folded QKV projection (unchanged r16).
// ---------------------------------------------------------------------------
__global__ __launch_bounds__(512) void k_ln_qkv(
    const float* __restrict__ x, const short* __restrict__ wqkv, const float2* __restrict__ gb,
    short* __restrict__ q, short* __restrict__ k, short* __restrict__ v)
{
    __shared__ short xnT[32 * 264];
    __shared__ short st2[128 * 48];
    __shared__ float ps_[8 * 32], ps2_[8 * 32];
    const int b   = blockIdx.y;
    const int l0  = blockIdx.x * 32;
    const int tid = threadIdx.x;
    const int wave = tid >> 6, lane = tid & 63;

    {
        const int ls = tid & 31;
        const int cg = tid >> 5;
        float s = 0.f, s2 = 0.f;
        #pragma unroll
        for (int kk = 0; kk < 8; ++kk) {
            int c = 2 * cg + 32 * kk;
            float t0 = x[((size_t)b * CC_ + c) * LL_ + l0 + ls];
            float t1 = x[((size_t)b * CC_ + c + 1) * LL_ + l0 + ls];
            s += t0 + t1; s2 += t0 * t0 + t1 * t1;
            unsigned pk = (unsigned short)f2bf(t0) | ((unsigned)(unsigned short)f2bf(t1) << 16);
            *(unsigned*)(xnT + ls * 264 + c) = pk;
        }
        s  += __shfl_xor(s, 32, 64);
        s2 += __shfl_xor(s2, 32, 64);
        if (lane < 32) { ps_[wave * 32 + lane] = s; ps2_[wave * 32 + lane] = s2; }
    }
    __syncthreads();

    const int n = lane & 15, quad = lane >> 4;
    const int rowbase = (wave >> 2) * 16;
    const int colbase = (wave & 3) * 96;

    v4f acc[6];
    #pragma unroll
    for (int ct = 0; ct < 6; ++ct) acc[ct] = (v4f){0.f, 0.f, 0.f, 0.f};

    #pragma unroll
    for (int ks = 0; ks < 8; ++ks) {
        const v8s af = *(const v8s*)(xnT + (rowbase + n) * 264 + ks * 32 + quad * 8);
        #pragma unroll
        for (int ct = 0; ct < 6; ++ct) {
            const v8s bfrag = *(const v8s*)(wqkv + (size_t)(colbase + ct * 16 + n) * 256 + ks * 32 + quad * 8);
            acc[ct] = __builtin_amdgcn_mfma_f32_16x16x32_bf16(af, bfrag, acc[ct], 0, 0, 0);
        }
    }
    __syncthreads();

    float rsv[4], rmv[4];
    #pragma unroll
    for (int r = 0; r < 4; ++r) {
        int l = rowbase + quad * 4 + r;
        float s = 0.f, s2 = 0.f;
        #pragma unroll
        for (int p = 0; p < 8; ++p) { s += ps_[p * 32 + l]; s2 += ps2_[p * 32 + l]; }
        float mean = s * (1.f / CC_);
        float var  = s2 * (1.f / CC_) - mean * mean;
        float rs   = rsqrtf(var + EPS_);
        rsv[r] = rs; rmv[r] = rs * mean;
    }
    #pragma unroll
    for (int ct = 0; ct < 6; ++ct) {
        int o = colbase + ct * 16 + n;
        float2 gbo = gb[o];
        #pragma unroll
        for (int r = 0; r < 4; ++r) {
            int l = rowbase + quad * 4 + r;
            float val = rsv[r] * acc[ct][r] - rmv[r] * gbo.x + gbo.y;
            if (o < 256)      xnT[l * 264 + o] = f2bf(val);
            else              st2[(o - 256) * 48 + l] = f2bf(val);
        }
    }
    __syncthreads();

    {
        int u = tid;
        int h = u >> 7, rest = u & 127;
        int l = rest >> 2, dg = rest & 3;
        size_t bh = (size_t)b * HEADS_ + h;
        v8s qv = *(const v8s*)(xnT + l * 264 + h * 32 + dg * 8);
        *(v8s*)(q + (bh * LL_ + l0 + l) * DHEAD_ + dg * 8) = qv;
        v8s kv = *(const v8s*)(xnT + l * 264 + 128 + h * 32 + dg * 8);
        *(v8s*)(k + (bh * LL_ + l0 + l) * DHEAD_ + dg * 8) = kv;

        int op = u >> 2, lg = u & 3;
        v8s vv = *(const v8s*)(st2 + op * 48 + lg * 8);
        int h2 = op >> 5, d = op & 31;
        *(v8s*)(v + (((size_t)b * HEADS_ + h2) * DHEAD_ + d) * LL_ + l0 + lg * 8) = vv;
    }
}

// ---------------------------------------------------------------------------
// Kernel 2: flash attention — r16 structure restored (512 thr = 4 q-waves x
// 2 key-halves, q-tile 128, register-dbuf staging) + XCD-AWARE SWIZZLE:
// all 16 q-blocks of one bh share linear_id % 8 (same XCD) so K/V is
// fetched from HBM once per XCD group instead of replicated 8x.
// ---------------------------------------------------------------------------
__global__ __launch_bounds__(512) void k_attn(
    const short* __restrict__ q, const short* __restrict__ k, const short* __restrict__ v,
    short* __restrict__ ao)
{
    __shared__ char smem[20480 + 17408 + 512];
    short* Kb     = (short*)smem;                      // [2][128*40]  (hh*5120)
    short* Vb     = (short*)(smem + 20480);            // [2][32*136]  (hh*4352)
    float* Ost    = (float*)smem;                      // alias Kb: [4][32][32]
    float* psumst = (float*)(smem + 20480 + 17408);    // [4*32]

    // XCD swizzle: linear id -> (bh, qx) with all qx of one bh on one XCD
    const int linear = blockIdx.y * 16 + blockIdx.x;   // grid (16, 32)
    const int cxy = linear & 7, j = linear >> 3;
    const int bh = cxy + 8 * (j >> 4);                 // bh % 8 == XCD id
    const int qx = j & 15;

    const int b    = bh >> 2, h = bh & 3;
    const int tid  = threadIdx.x;
    const int wave = tid >> 6, lane = tid & 63;
    const int wq   = wave & 3;           // q-subtile
    const int kh   = wave >> 2;          // key half: [kh*1024, +1024)
    const int m    = lane & 31;
    const int half = lane >> 5;
    const size_t kvbase = (size_t)bh * LL_ * DHEAD_;   // q,k: [bh][l][32]
    const size_t vbase  = (size_t)bh * DHEAD_ * LL_;   // v:   [bh][d][L]

    const int q0 = qx * 128 + wq * 32;

    const v8s qf0 = *(const v8s*)(q + kvbase + (size_t)(q0 + m) * DHEAD_ + half * 8);
    const v8s qf1 = *(const v8s*)(q + kvbase + (size_t)(q0 + m) * DHEAD_ + 16 + half * 8);

    v16f O = {};
    float psum = 0.f;

    // staging coords (whole block stages both halves each chunk)
    const int s_hh  = (tid >> 7) & 1;     // which key-half for K staging
    const int s_r   = tid & 127;          // key row
    const int s_p   = tid >> 8;           // 16-half part (0/1)
    const int v_hh  = tid >> 8;           // which key-half for V staging
    const int v_d   = (tid >> 3) & 31;    // d row
    const int v_cg  = tid & 7;            // 16-half col group

    const short* ksrc0 = k + kvbase + (size_t)(s_hh * 1024 + s_r) * DHEAD_ + s_p * 16;
    const short* vsrc0 = v + vbase + (size_t)v_d * LL_ + v_hh * 1024 + v_cg * 16;
    short* kdst = Kb + s_hh * 5120 + s_r * 40 + s_p * 16;
    short* vdst = Vb + v_hh * 4352 + v_d * 136 + v_cg * 16;

    // prologue: chunk 0 into registers
    v8s kr0 = *(const v8s*)(ksrc0);
    v8s kr1 = *(const v8s*)(ksrc0 + 8);
    v8s vr0 = *(const v8s*)(vsrc0);
    v8s vr1 = *(const v8s*)(vsrc0 + 8);

    for (int kc = 0; kc < 1024; kc += 128) {
        __syncthreads();   // previous chunk's readers done
        *(v8s*)kdst       = kr0;
        *(v8s*)(kdst + 8) = kr1;
        *(v8s*)vdst       = vr0;
        *(v8s*)(vdst + 8) = vr1;
        if (kc < 896) {    // prefetch next chunk; completes during compute
            const short* kn = ksrc0 + (size_t)(kc + 128) * DHEAD_;
            const short* vn = vsrc0 + (kc + 128);
            kr0 = *(const v8s*)(kn);
            kr1 = *(const v8s*)(kn + 8);
            vr0 = *(const v8s*)(vn);
            vr1 = *(const v8s*)(vn + 8);
        }
        __syncthreads();   // staging visible

        const short* Kw = Kb + kh * 5120;
        const short* Vw = Vb + kh * 4352;
        #pragma unroll
        for (int ktl = 0; ktl < 128; ktl += 32) {
            const v8s kf0 = *(const v8s*)(Kw + (ktl + m) * 40 + half * 8);
            const v8s kf1 = *(const v8s*)(Kw + (ktl + m) * 40 + 16 + half * 8);
            v16f S = __builtin_amdgcn_mfma_f32_32x32x16_bf16(kf0, qf0, (v16f){}, 0, 0, 0);
            S      = __builtin_amdgcn_mfma_f32_32x32x16_bf16(kf1, qf1, S,        0, 0, 0);

            const v8s vf0 = *(const v8s*)(Vw + m * 136 + ktl + half * 8);
            const v8s vf1 = *(const v8s*)(Vw + m * 136 + ktl + 16 + half * 8);

            unsigned e[8];
            #pragma unroll
            for (int i = 0; i < 8; ++i) {
                float pa = __builtin_amdgcn_exp2f(S[2 * i]);
                float pb = __builtin_amdgcn_exp2f(S[2 * i + 1]);
                psum += pa + pb;
                e[i] = __builtin_amdgcn_perm(fbits(pb) + 0x8000u, fbits(pa) + 0x8000u, 0x07060302u);
            }
            v4u f1, f2;
#if __has_builtin(__builtin_amdgcn_permlane32_swap)
            {
                auto r02 = __builtin_amdgcn_permlane32_swap(e[0], e[2], false, false);
                auto r13 = __builtin_amdgcn_permlane32_swap(e[1], e[3], false, false);
                auto r46 = __builtin_amdgcn_permlane32_swap(e[4], e[6], false, false);
                auto r57 = __builtin_amdgcn_permlane32_swap(e[5], e[7], false, false);
                f1 = (v4u){r02[0], r13[0], r02[1], r13[1]};
                f2 = (v4u){r46[0], r57[0], r46[1], r57[1]};
            }
#else
            {
                unsigned o0 = __shfl_xor(e[0], 32, 64), o1 = __shfl_xor(e[1], 32, 64);
                unsigned o2 = __shfl_xor(e[2], 32, 64), o3 = __shfl_xor(e[3], 32, 64);
                unsigned o4 = __shfl_xor(e[4], 32, 64), o5 = __shfl_xor(e[5], 32, 64);
                unsigned o6 = __shfl_xor(e[6], 32, 64), o7 = __shfl_xor(e[7], 32, 64);
                f1 = half ? (v4u){o2, o3, e[2], e[3]} : (v4u){e[0], e[1], o0, o1};
                f2 = half ? (v4u){o6, o7, e[6], e[7]} : (v4u){e[4], e[5], o4, o5};
            }
#endif
            O = __builtin_amdgcn_mfma_f32_32x32x16_bf16(__builtin_bit_cast(v8s, f1), vf0, O, 0, 0, 0);
            O = __builtin_amdgcn_mfma_f32_32x32x16_bf16(__builtin_bit_cast(v8s, f2), vf1, O, 0, 0, 0);
        }
    }

    psum += __shfl_xor(psum, 32, 64);    // lane m: den-partial for q = m

    __syncthreads();   // all waves done reading Kb before Ost (alias) writes
    if (kh == 1) {
        #pragma unroll
        for (int r = 0; r < 16; ++r) {
            int qr = (r & 3) + 8 * (r >> 2) + 4 * half;
            Ost[(wq * 32 + qr) * 32 + m] = O[r];
        }
        if (half == 0) psumst[wq * 32 + m] = psum;
    }
    __syncthreads();
    if (kh == 0) {
        float den = psum + psumst[wq * 32 + m];
        float invden = 1.f / den;
        #pragma unroll
        for (int r = 0; r < 16; ++r) {
            int qr = (r & 3) + 8 * (r >> 2) + 4 * half;
            float inv = __shfl(invden, qr, 64);
            float val = (O[r] + Ost[(wq * 32 + qr) * 32 + m]) * inv;
            int row = q0 + qr;
            ao[((size_t)b * LL_ + row) * HID_ + h * DHEAD_ + m] = f2bf(val);
        }
    }
}

// ---------------------------------------------------------------------------
// Kernel 3: output projection (unchanged r16).
// ---------------------------------------------------------------------------
__global__ __launch_bounds__(256) void k_oproj(
    const short* __restrict__ ao, const short* __restrict__ wo, const float* __restrict__ bo,
    const float* __restrict__ x, float* __restrict__ out)
{
    const int b = blockIdx.z;
    const int l0 = blockIdx.x * 32;
    const int tid = threadIdx.x;
    const int wave = tid >> 6, lane = tid & 63;
    const int m = lane & 31, half = lane >> 5;
    const int o0 = blockIdx.y * 128 + wave * 32;

    float xv[16]; float bv_[16];
    #pragma unroll
    for (int r = 0; r < 16; ++r) {
        int o = o0 + (r & 3) + 8 * (r >> 2) + 4 * half;
        xv[r]  = x[((size_t)b * CC_ + o) * LL_ + l0 + m];
        bv_[r] = bo[o];
    }

    v8s bf[8];
    #pragma unroll
    for (int ks = 0; ks < 8; ++ks)
        bf[ks] = *(const v8s*)(ao + ((size_t)b * LL_ + l0 + m) * HID_ + ks * 16 + half * 8);

    v16f acc = {};
    #pragma unroll
    for (int ks = 0; ks < 8; ++ks) {
        const v8s af = *(const v8s*)(wo + (size_t)(o0 + m) * HID_ + ks * 16 + half * 8);
        acc = __builtin_amdgcn_mfma_f32_32x32x16_bf16(af, bf[ks], acc, 0, 0, 0);
    }

    #pragma unroll
    for (int r = 0; r < 16; ++r) {
        int o = o0 + (r & 3) + 8 * (r >> 2) + 4 * half;
        size_t oi = ((size_t)b * CC_ + o) * LL_ + l0 + m;
        out[oi] = acc[r] + bv_[r] + xv[r];
    }
}

extern "C" void kernel_launch(void* const* d_in, const int* in_sizes, int n_in,
                              void* d_out, int out_size, void* d_ws, size_t ws_size,
                              hipStream_t stream) {
    const float* x  = (const float*)d_in[0];
    const float* g  = (const float*)d_in[1];
    const float* bv = (const float*)d_in[2];
    const float* Wq = (const float*)d_in[3];
    const float* Wk = (const float*)d_in[4];
    const float* Wv = (const float*)d_in[5];
    const float* Wo = (const float*)d_in[6];
    const float* bo = (const float*)d_in[7];
    float* out = (float*)d_out;

    const size_t qkv_elems = (size_t)BB_ * HEADS_ * LL_ * DHEAD_;
    short* q    = (short*)d_ws;
    short* k    = q + qkv_elems;
    short* v    = k + qkv_elems;
    short* ao   = v + qkv_elems;
    short* wqkv = ao + qkv_elems;
    short* wo   = wqkv + 384 * 256;
    float2* gb  = (float2*)(wo + 256 * 128);

    k_prep  <<<dim3(512), dim3(256), 0, stream>>>(Wq, Wk, Wv, Wo, g, bv, wqkv, wo, gb);
    k_ln_qkv<<<dim3(LL_ / 32, BB_), dim3(512), 0, stream>>>(x, wqkv, gb, q, k, v);
    k_attn  <<<dim3(LL_ / 128, BB_ * HEADS_), dim3(512), 0, stream>>>(q, k, v, ao);
    k_oproj <<<dim3(LL_ / 32, 2, BB_), dim3(256), 0, stream>>>(ao, wo, bo, x, out);
}